// Round 4
// baseline (531.422 us; speedup 1.0000x reference)
//
#include <hip/hip_runtime.h>

// Geometry (fixed by the problem)
constexpr int B_ = 4, CIN_ = 8, Hd = 64, Wd = 64;
constexpr int COUT_ = 32, KH_ = 3, KW_ = 3;
constexpr int K_ = CIN_ * KH_ * KW_;      // 72
constexpr int L_ = Hd * Wd;               // 4096
constexpr int POT_SIZE = B_ * COUT_ * L_; // 524288 (also the k-stride of traces_folded)

typedef float v4f __attribute__((ext_vector_type(4)));

// ---------------------------------------------------------------------------
// Kernel 1: pot. Reads delay + delay_init (302 MB), computes the K-reduction
// of (delay + xu*delay_init == 1) * w[o,k], atomicAdds partials into out[0..POT).
// K split into 8 chunks (1 input channel each) -> 4096 blocks -> full occupancy.
// Runs FIRST so the L3-resident (just-restored) delay/delay_init get harvested
// before the trace kernel's streams evict them.
// ---------------------------------------------------------------------------
constexpr int NCHUNK = 8;

__global__ __launch_bounds__(256)
void pot_kernel(const float* __restrict__ x,
                const float* __restrict__ weight,
                const float* __restrict__ delay,
                const float* __restrict__ delay_init,
                float* __restrict__ out)
{
    const int bid   = blockIdx.x;
    const int c     = bid >> 9;               // 0..7 (chunk == input channel)
    const int rem   = bid & 511;
    const int bo    = rem >> 2;               // b*COUT + o
    const int qrt   = rem & 3;
    const int l     = qrt * 1024 + threadIdx.x * 4;
    const int b  = bo >> 5;
    const int o  = bo & 31;
    const int ho = l >> 6;
    const int wo = l & 63;

    const float* xc   = x + (b * CIN_ + c) * (Hd * Wd);
    const float* wrow = weight + o * K_;

    const int base = bo * (K_ * L_) + l;
    const float* dptr  = delay + base;
    const float* diptr = delay_init + base;

    float px = 0.f, py = 0.f, pz = 0.f, pw = 0.f;

    int k = c * (KH_ * KW_);
    #pragma unroll
    for (int kh = 0; kh < KH_; ++kh) {
        const int h = ho - 1 + kh;
        const bool hok = (unsigned)h < (unsigned)Hd;
        const float* xr = xc + h * Wd;
        float xv[6];
        #pragma unroll
        for (int j = 0; j < 6; ++j) {
            const int w = wo - 1 + j;
            xv[j] = (hok && (unsigned)w < (unsigned)Wd) ? xr[w] : 0.0f;
        }
        #pragma unroll
        for (int kw = 0; kw < KW_; ++kw, ++k) {
            const v4f d  = __builtin_nontemporal_load(
                reinterpret_cast<const v4f*>(dptr  + k * L_));
            const v4f di = __builtin_nontemporal_load(
                reinterpret_cast<const v4f*>(diptr + k * L_));
            const float wk = wrow[k];
            px += (d.x + xv[kw + 0] * di.x == 1.0f) ? wk : 0.0f;
            py += (d.y + xv[kw + 1] * di.y == 1.0f) ? wk : 0.0f;
            pz += (d.z + xv[kw + 2] * di.z == 1.0f) ? wk : 0.0f;
            pw += (d.w + xv[kw + 3] * di.w == 1.0f) ? wk : 0.0f;
        }
    }

    float* p = out + bo * L_ + l;
    atomicAdd(p + 0, px);
    atomicAdd(p + 1, py);
    atomicAdd(p + 2, pz);
    atomicAdd(p + 3, pw);
}

// ---------------------------------------------------------------------------
// Kernel 2: trace. Pure 1R+1W stream (copy-shaped): trace_new = t + r*(alpha*xu - t).
// One block per (b,o,k) row of 4096 floats; each thread handles 16 contiguous
// floats (one ho row segment, so h is fixed per thread). NT loads + stores.
// 9216 blocks.
// ---------------------------------------------------------------------------
__global__ __launch_bounds__(256)
void trace_kernel(const float* __restrict__ x,
                  const float* __restrict__ trace,
                  const float* __restrict__ alpha_p,
                  const float* __restrict__ tau_p,
                  const float* __restrict__ dt_p,
                  float* __restrict__ out)
{
    const float alpha = alpha_p[0];
    const float r = dt_p[0] / tau_p[0];

    const int bid = blockIdx.x;           // bo*K + k
    const int bo  = bid / K_;
    const int k   = bid - bo * K_;
    const int b   = bo >> 5;
    const int c   = k / (KH_ * KW_);
    const int k9  = k - c * (KH_ * KW_);
    const int kh  = k9 / KW_;
    const int kw  = k9 - kh * KW_;

    const int tid = threadIdx.x;
    const int l0  = tid * 16;
    const int ho  = tid >> 2;             // l0 >> 6
    const int wox = (tid & 3) * 16;

    const int h = ho - 1 + kh;
    const bool hok = (unsigned)h < (unsigned)Hd;
    const float* xr = x + (b * CIN_ + c) * (Hd * Wd) + h * Wd;
    const int wbase = wox - 1 + kw;

    float xu[16];
    #pragma unroll
    for (int j = 0; j < 16; ++j) {
        const int w = wbase + j;
        xu[j] = (hok && (unsigned)w < (unsigned)Wd) ? xr[w] : 0.0f;
    }

    const float* tin = trace + (bo * K_ + k) * L_ + l0;
    float* tout = out + POT_SIZE + k * POT_SIZE + bo * L_ + l0;

    v4f t0 = __builtin_nontemporal_load(reinterpret_cast<const v4f*>(tin + 0));
    v4f t1 = __builtin_nontemporal_load(reinterpret_cast<const v4f*>(tin + 4));
    v4f t2 = __builtin_nontemporal_load(reinterpret_cast<const v4f*>(tin + 8));
    v4f t3 = __builtin_nontemporal_load(reinterpret_cast<const v4f*>(tin + 12));

    v4f r0, r1, r2, r3;
    #pragma unroll
    for (int j = 0; j < 4; ++j) {
        r0[j] = t0[j] + r * (alpha * xu[j]      - t0[j]);
        r1[j] = t1[j] + r * (alpha * xu[4 + j]  - t1[j]);
        r2[j] = t2[j] + r * (alpha * xu[8 + j]  - t2[j]);
        r3[j] = t3[j] + r * (alpha * xu[12 + j] - t3[j]);
    }

    __builtin_nontemporal_store(r0, reinterpret_cast<v4f*>(tout + 0));
    __builtin_nontemporal_store(r1, reinterpret_cast<v4f*>(tout + 4));
    __builtin_nontemporal_store(r2, reinterpret_cast<v4f*>(tout + 8));
    __builtin_nontemporal_store(r3, reinterpret_cast<v4f*>(tout + 12));
}

extern "C" void kernel_launch(void* const* d_in, const int* in_sizes, int n_in,
                              void* d_out, int out_size, void* d_ws, size_t ws_size,
                              hipStream_t stream) {
    const float* x          = (const float*)d_in[0];
    const float* weight     = (const float*)d_in[1];
    const float* trace      = (const float*)d_in[2];
    const float* delay      = (const float*)d_in[3];
    const float* delay_init = (const float*)d_in[4];
    const float* alpha_t    = (const float*)d_in[5];
    const float* tau_t      = (const float*)d_in[6];
    const float* dt         = (const float*)d_in[7];
    float* out = (float*)d_out;

    (void)hipMemsetAsync(out, 0, POT_SIZE * sizeof(float), stream);

    // pot first: harvest L3 residency of freshly-restored delay/delay_init.
    pot_kernel<<<NCHUNK * 512, 256, 0, stream>>>(x, weight, delay, delay_init, out);

    trace_kernel<<<B_ * COUT_ * K_, 256, 0, stream>>>(x, trace, alpha_t, tau_t, dt, out);
}

// Round 5
// 442.827 us; speedup vs baseline: 1.2001x; 1.2001x over previous
//
#include <hip/hip_runtime.h>

// Geometry (fixed by the problem)
constexpr int B_ = 4, CIN_ = 8, Hd = 64, Wd = 64;
constexpr int COUT_ = 32, KH_ = 3, KW_ = 3;
constexpr int K_ = CIN_ * KH_ * KW_;      // 72
constexpr int L_ = Hd * Wd;               // 4096
constexpr int POT_SIZE = B_ * COUT_ * L_; // 524288 (also the k-stride of traces_folded)

typedef float v4f __attribute__((ext_vector_type(4)));

// Fused single-pass kernel (R3 structure — measured best at 114 us), with the
// K=72 reduction split into 8 chunks of 1 input channel -> 4096 blocks
// (2x wave oversubscription; R3's 2048 filled the machine exactly 1x and
// showed 35% occupancy from drain/imbalance). Partial pot via atomicAdd into
// the pre-zeroed pot region (8 RMW per address — negligible vs 600 MB streamed).
constexpr int NCHUNK = 8;

__global__ __launch_bounds__(256)
void fused_conv_delay_trace(const float* __restrict__ x,
                            const float* __restrict__ weight,
                            const float* __restrict__ trace,
                            const float* __restrict__ delay,
                            const float* __restrict__ delay_init,
                            const float* __restrict__ alpha_p,
                            const float* __restrict__ tau_p,
                            const float* __restrict__ dt_p,
                            float* __restrict__ out)
{
    const float alpha = alpha_p[0];
    const float r = dt_p[0] / tau_p[0];

    const int bid   = blockIdx.x;
    const int c     = bid >> 9;               // 0..7: chunk == input channel
    const int rem   = bid & 511;
    const int bo    = rem >> 2;               // b*COUT + o   (0..127)
    const int qrt   = rem & 3;                // quarter of L
    const int l     = qrt * 1024 + threadIdx.x * 4;
    const int b  = bo >> 5;                   // / COUT
    const int o  = bo & 31;                   // % COUT
    const int ho = l >> 6;
    const int wo = l & 63;

    const float* xc   = x + (b * CIN_ + c) * (Hd * Wd);
    const float* wrow = weight + o * K_;

    const int base = bo * (K_ * L_) + l;      // into [B,COUT,K,L]
    const float* tptr  = trace + base;
    const float* dptr  = delay + base;
    const float* diptr = delay_init + base;
    float* tout = out + POT_SIZE + bo * L_ + l;   // traces_folded, k-stride = POT_SIZE

    float px = 0.f, py = 0.f, pz = 0.f, pw = 0.f;

    int k = c * (KH_ * KW_);
    #pragma unroll
    for (int kh = 0; kh < KH_; ++kh) {
        const int h = ho - 1 + kh;
        const bool hok = (unsigned)h < (unsigned)Hd;
        const float* xr = xc + h * Wd;
        // x row segment w = wo-1 .. wo+4 (covers kw=0..2, j=0..3)
        float xv[6];
        #pragma unroll
        for (int j = 0; j < 6; ++j) {
            const int w = wo - 1 + j;
            xv[j] = (hok && (unsigned)w < (unsigned)Wd) ? xr[w] : 0.0f;
        }
        #pragma unroll
        for (int kw = 0; kw < KW_; ++kw, ++k) {
            const v4f d  = __builtin_nontemporal_load(
                reinterpret_cast<const v4f*>(dptr  + k * L_));
            const v4f t  = __builtin_nontemporal_load(
                reinterpret_cast<const v4f*>(tptr  + k * L_));
            const v4f di = __builtin_nontemporal_load(
                reinterpret_cast<const v4f*>(diptr + k * L_));
            const float wk = wrow[k];
            const float xu0 = xv[kw + 0];
            const float xu1 = xv[kw + 1];
            const float xu2 = xv[kw + 2];
            const float xu3 = xv[kw + 3];
            v4f tn;
            tn.x = t.x + r * (alpha * xu0 - t.x);
            tn.y = t.y + r * (alpha * xu1 - t.y);
            tn.z = t.z + r * (alpha * xu2 - t.z);
            tn.w = t.w + r * (alpha * xu3 - t.w);
            __builtin_nontemporal_store(tn,
                reinterpret_cast<v4f*>(tout + k * POT_SIZE));
            px += (d.x + xu0 * di.x == 1.0f) ? wk : 0.0f;
            py += (d.y + xu1 * di.y == 1.0f) ? wk : 0.0f;
            pz += (d.z + xu2 * di.z == 1.0f) ? wk : 0.0f;
            pw += (d.w + xu3 * di.w == 1.0f) ? wk : 0.0f;
        }
    }

    float* p = out + bo * L_ + l;
    atomicAdd(p + 0, px);
    atomicAdd(p + 1, py);
    atomicAdd(p + 2, pz);
    atomicAdd(p + 3, pw);
}

extern "C" void kernel_launch(void* const* d_in, const int* in_sizes, int n_in,
                              void* d_out, int out_size, void* d_ws, size_t ws_size,
                              hipStream_t stream) {
    const float* x          = (const float*)d_in[0];
    const float* weight     = (const float*)d_in[1];
    const float* trace      = (const float*)d_in[2];
    const float* delay      = (const float*)d_in[3];
    const float* delay_init = (const float*)d_in[4];
    const float* alpha_t    = (const float*)d_in[5];
    const float* tau_t      = (const float*)d_in[6];
    const float* dt         = (const float*)d_in[7];
    float* out = (float*)d_out;

    // zero the pot region (first POT_SIZE floats); trace region is fully
    // overwritten by the kernel's stores.
    (void)hipMemsetAsync(out, 0, POT_SIZE * sizeof(float), stream);

    const int blocks = NCHUNK * B_ * COUT_ * (L_ / 4) / 256;  // 4096
    fused_conv_delay_trace<<<blocks, 256, 0, stream>>>(
        x, weight, trace, delay, delay_init, alpha_t, tau_t, dt, out);
}